// Round 6
// baseline (534.753 us; speedup 1.0000x reference)
//
#include <hip/hip_runtime.h>
#include <hip/hip_bf16.h>
#include <stdint.h>

typedef unsigned short ushort_t;
typedef __attribute__((ext_vector_type(8))) short short8;
typedef __attribute__((ext_vector_type(4))) float floatx4;
typedef __attribute__((ext_vector_type(16))) float floatx16;

__device__ __forceinline__ ushort_t f2b(float f) {
    unsigned u = __float_as_uint(f);
    unsigned r = (u + 0x7FFFu + ((u >> 16) & 1u)) >> 16;
    return (ushort_t)r;
}
__device__ __forceinline__ float b2f(ushort_t h) {
    return __uint_as_float(((unsigned)h) << 16);
}
__device__ __forceinline__ float elu1(float f) {
    return (f > 0.f) ? (f + 1.f) : __expf(f);
}
__device__ __forceinline__ unsigned cvtpk(float lo, float hi) {
    unsigned w;
    asm("v_cvt_pk_bf16_f32 %0, %1, %2" : "=v"(w) : "v"(lo), "v"(hi));
    return w;
}

#define GLDS16(srcp, dstp)                                                          \
    __builtin_amdgcn_global_load_lds(                                               \
        (const __attribute__((address_space(1))) unsigned int*)(srcp),              \
        (__attribute__((address_space(3))) unsigned int*)(dstp), 16, 0, 0)

// ---------------- conversion kernels ----------------

__global__ void conv_bf16(const float* __restrict__ in, ushort_t* __restrict__ out, int n8) {
    for (int i = blockIdx.x * blockDim.x + threadIdx.x; i < n8; i += gridDim.x * blockDim.x) {
        const float4 f0 = *(const float4*)&in[(size_t)i * 8];
        const float4 f1 = *(const float4*)&in[(size_t)i * 8 + 4];
        ushort4 o0, o1;
        o0.x = f2b(f0.x); o0.y = f2b(f0.y); o0.z = f2b(f0.z); o0.w = f2b(f0.w);
        o1.x = f2b(f1.x); o1.y = f2b(f1.y); o1.z = f2b(f1.z); o1.w = f2b(f1.w);
        *(ushort4*)&out[(size_t)i * 8]     = o0;
        *(ushort4*)&out[(size_t)i * 8 + 4] = o1;
    }
}

__global__ void transpose_conv(const float* __restrict__ in, ushort_t* __restrict__ out,
                               int R, int C) {
    __shared__ float tile[32][33];
    int c0 = blockIdx.x * 32, r0 = blockIdx.y * 32;
    int tx = threadIdx.x, ty = threadIdx.y;
#pragma unroll
    for (int k = 0; k < 4; ++k) {
        int a = ty * 4 + k;
        tile[a][tx] = in[(size_t)(r0 + a) * C + c0 + tx];
    }
    __syncthreads();
#pragma unroll
    for (int k = 0; k < 4; ++k) {
        int a = ty * 4 + k;
        out[(size_t)(c0 + a) * R + r0 + tx] = f2b(tile[tx][a]);
    }
}

__global__ void zero_f32(float* __restrict__ p, int n) {
    int i = blockIdx.x * blockDim.x + threadIdx.x;
    if (i < n) p[i] = 0.f;
}

// ---------------- 256x256 8-phase GEMM (32x32x16 MFMA): C = A @ Bt^T, K=1024 ----------------
// Swapped-operand MFMA: lane&31 = token m; reg-dim = n cols (4 consecutive per 4-reg group).
// MODE 0: qkv epilogue: bias + elu+1 on q,k; packed 8B scatter to [3][bh][8192][64]
// MODE 1: proj epilogue: bias; fp32 linear [M][Nt]
template<int MODE>
__global__ __launch_bounds__(512, 2) void gemm256(
    const ushort_t* __restrict__ A, const ushort_t* __restrict__ Bt,
    const float* __restrict__ bias,
    ushort_t* __restrict__ out_u16, float* __restrict__ out_f32,
    int Nt, int nbx)
{
    extern __shared__ ushort_t lds[];   // 65536 elements = 128 KiB
    constexpr int KK = 1024;

    const int tid  = threadIdx.x;
    const int wave = tid >> 6;
    const int lane = tid & 63;
    const int wm_i = wave >> 2;
    const int wn_i = wave & 3;
    const int ml   = lane & 31;      // m-token offset within 32-tile
    const int fh   = lane >> 5;      // k-half selector

    // XCD-bijective block swizzle (grid % 8 == 0)
    const int nwg = (int)gridDim.x;
    const int bid = (int)blockIdx.x;
    const int swz = (bid & 7) * (nwg >> 3) + (bid >> 3);
    const int bx = swz % nbx, by = swz / nbx;
    const int m0 = by * 256, n0 = bx * 256;

    // staging per-thread constants (unchanged slot layout, write-side pre-swizzle)
    const int trow = tid >> 3;
    const int csw  = ((tid & 7) ^ (trow & 7)) << 3;
    const int tcolB = ((tid >> 8) << 6) + (trow & 31);

    const ushort_t* sa = A  + (size_t)(m0 + trow)  * KK + csw;
    const ushort_t* sb = Bt + (size_t)(n0 + tcolB) * KK + csw;

    const int dstA = wave * 512;
    const int dstB = 16384 + wave * 512;

    // ds_read per-lane constants: phys chunk = (s*2 + fh) ^ (row&7), row&7 == lane&7
    int pcs[4];
#pragma unroll
    for (int s = 0; s < 4; ++s) pcs[s] = (((s * 2 + fh) ^ (lane & 7)) << 3);
    const int rbA = (wm_i * 64 + ml) << 6;
    const int rbB = (wn_i * 32 + ml) << 6;

    floatx16 acc[4][2];
#pragma unroll
    for (int i = 0; i < 4; ++i)
#pragma unroll
        for (int j = 0; j < 2; ++j)
#pragma unroll
            for (int e = 0; e < 16; ++e) acc[i][j][e] = 0.f;

    short8 a32[2][4], b32[4];

    auto stageA = [&](int buf, int h, int ko) {
        ushort_t* d = lds + buf * 32768 + h * 8192 + dstA;
        GLDS16(sa + h * (64 * KK) + ko, d);
        GLDS16(sa + h * (64 * KK) + 128 * KK + ko, d + 4096);
    };
    auto stageB = [&](int buf, int h, int ko) {
        ushort_t* d = lds + buf * 32768 + h * 8192 + dstB;
        GLDS16(sb + h * (32 * KK) + ko, d);
        GLDS16(sb + h * (32 * KK) + 128 * KK + ko, d + 4096);
    };
    auto loadA = [&](int buf, int qr) {
        const int base = buf * 32768 + qr * 8192 + rbA;
#pragma unroll
        for (int i = 0; i < 2; ++i)
#pragma unroll
            for (int s = 0; s < 4; ++s)
                a32[i][s] = *(const short8*)(lds + base + i * 2048 + pcs[s]);
    };
    auto loadB = [&](int buf, int qc) {
        const int base = buf * 32768 + 16384 + qc * 8192 + rbB;
#pragma unroll
        for (int s = 0; s < 4; ++s)
            b32[s] = *(const short8*)(lds + base + pcs[s]);
    };
    // swapped operands: mfma(b, a) -> lane&31 = m-token, reg-dim = n
    auto mma = [&](int qr, int qc) {
#pragma unroll
        for (int s = 0; s < 4; ++s) {
            acc[qr * 2 + 0][qc] =
                __builtin_amdgcn_mfma_f32_32x32x16_bf16(b32[s], a32[0][s], acc[qr * 2 + 0][qc], 0, 0, 0);
            acc[qr * 2 + 1][qc] =
                __builtin_amdgcn_mfma_f32_32x32x16_bf16(b32[s], a32[1][s], acc[qr * 2 + 1][qc], 0, 0, 0);
        }
    };

#define PRIO1() __builtin_amdgcn_s_setprio(1)
#define BOUT()  __builtin_amdgcn_s_setprio(0); __builtin_amdgcn_s_barrier()
#define VM6()   asm volatile("s_waitcnt vmcnt(6)" ::: "memory")
#define VM0()   asm volatile("s_waitcnt vmcnt(0)" ::: "memory")

    // prologue: stream order per tile = [A0, B1, A1, B0]
    stageA(0, 0, 0);
    stageB(0, 1, 0);
    stageA(0, 1, 0);
    stageB(0, 0, 0);
    stageA(1, 0, 64);
    stageB(1, 1, 64);
    stageA(1, 1, 64);
    VM6();
    __builtin_amdgcn_s_barrier();

    int ko = 0;
    for (int pr = 0; pr < 7; ++pr, ko += 128) {
        // ---- tile t0 (buf0) ----
        loadA(0, 0); loadB(0, 0);
        stageB(1, 0, ko + 64);
        PRIO1(); mma(0, 0); BOUT();

        loadB(0, 1);
        stageA(0, 0, ko + 128);
        PRIO1(); mma(0, 1); BOUT();

        loadA(0, 1);
        stageB(0, 1, ko + 128);
        PRIO1(); mma(1, 1); BOUT();

        loadB(0, 0);
        stageA(0, 1, ko + 128);
        PRIO1(); mma(1, 0); __builtin_amdgcn_s_setprio(0); VM6();
        __builtin_amdgcn_s_barrier();

        // ---- tile t0+1 (buf1) ----
        loadA(1, 0); loadB(1, 0);
        stageB(0, 0, ko + 128);
        PRIO1(); mma(0, 0); BOUT();

        loadB(1, 1);
        stageA(1, 0, ko + 192);
        PRIO1(); mma(0, 1); BOUT();

        loadA(1, 1);
        stageB(1, 1, ko + 192);
        PRIO1(); mma(1, 1); BOUT();

        loadB(1, 0);
        stageA(1, 1, ko + 192);
        PRIO1(); mma(1, 0); __builtin_amdgcn_s_setprio(0); VM6();
        __builtin_amdgcn_s_barrier();
    }

    // peeled last iteration: tiles 14 (buf0), 15 (buf1); ko == 896
    loadA(0, 0); loadB(0, 0);
    stageB(1, 0, 960);
    PRIO1(); mma(0, 0); BOUT();

    loadB(0, 1);
    PRIO1(); mma(0, 1); BOUT();

    loadA(0, 1);
    PRIO1(); mma(1, 1); BOUT();

    loadB(0, 0);
    PRIO1(); mma(1, 0); __builtin_amdgcn_s_setprio(0); VM0();
    __builtin_amdgcn_s_barrier();

    loadA(1, 0); loadB(1, 0);
    PRIO1(); mma(0, 0); BOUT();

    loadB(1, 1);
    PRIO1(); mma(0, 1); BOUT();

    loadA(1, 1);
    PRIO1(); mma(1, 1); BOUT();

    loadB(1, 0);
    PRIO1(); mma(1, 0);
    __builtin_amdgcn_s_setprio(0);

#undef PRIO1
#undef BOUT
#undef VM6
#undef VM0

    // epilogue:
    //   m = m0 + wm_i*128 + mt*32 + ml
    //   n = n0 + wn_i*64 + qch*32 + 8*g + 4*fh + (0..3)   [regs 4g..4g+3]
    float4 bvv[2][4];
#pragma unroll
    for (int qch = 0; qch < 2; ++qch)
#pragma unroll
        for (int g = 0; g < 4; ++g) {
            const int nb = n0 + wn_i * 64 + qch * 32 + 8 * g + 4 * fh;
            bvv[qch][g] = *(const float4*)&bias[nb];
        }
#pragma unroll
    for (int mt = 0; mt < 4; ++mt) {
        const int m = m0 + wm_i * 128 + mt * 32 + ml;
#pragma unroll
        for (int qch = 0; qch < 2; ++qch) {
#pragma unroll
            for (int g = 0; g < 4; ++g) {
                const int nb = n0 + wn_i * 64 + qch * 32 + 8 * g + 4 * fh;
                float v0 = acc[mt][qch][4 * g + 0] + bvv[qch][g].x;
                float v1 = acc[mt][qch][4 * g + 1] + bvv[qch][g].y;
                float v2 = acc[mt][qch][4 * g + 2] + bvv[qch][g].z;
                float v3 = acc[mt][qch][4 * g + 3] + bvv[qch][g].w;
                if (MODE == 0) {
                    const int s  = nb >> 10;
                    const int c  = nb & 1023;
                    const int hh = c >> 6;
                    const int d  = c & 63;
                    const int bb = m >> 13;
                    const int nt = m & 8191;
                    if (s < 2) { v0 = elu1(v0); v1 = elu1(v1); v2 = elu1(v2); v3 = elu1(v3); }
                    uint2 o;
                    o.x = cvtpk(v0, v1);
                    o.y = cvtpk(v2, v3);
                    *(uint2*)&out_u16[(((size_t)s * 64 + bb * 16 + hh) * 8192 + nt) * 64 + d] = o;
                } else {
                    float4 o; o.x = v0; o.y = v1; o.z = v2; o.w = v3;
                    *(float4*)&out_f32[(size_t)m * Nt + nb] = o;
                }
            }
        }
    }
}

// ---------------- kv = k^T v  (+ ksum) per (b,h) ----------------
// kbuf/vbuf: [64][8192][64] bf16 (already elu'd k).  kv: [64][64][64] fp32.  ksum: [64][64].
__global__ __launch_bounds__(256) void kv_kernel(
    const ushort_t* __restrict__ kbuf, const ushort_t* __restrict__ vbuf,
    float* __restrict__ kv, float* __restrict__ ksum)
{
    __shared__ ushort_t ks[64 * 64] __attribute__((aligned(16)));
    __shared__ ushort_t vs[64 * 64] __attribute__((aligned(16)));

    const int bh = blockIdx.y, chunk = blockIdx.x, t = threadIdx.x;
    const int d0 = (t >> 4) * 4, e0 = (t & 15) * 4;
    const bool do_ksum = (t & 15) == 0;

    float acc[4][4];
#pragma unroll
    for (int i = 0; i < 4; ++i)
#pragma unroll
        for (int j = 0; j < 4; ++j) acc[i][j] = 0.f;
    float kacc[4] = {0.f, 0.f, 0.f, 0.f};

    for (int sub = 0; sub < 8; ++sub) {
        const int nb = chunk * 512 + sub * 64;
        __syncthreads();
#pragma unroll
        for (int p = 0; p < 2; ++p) {
            int idx = p * 256 + t;
            int r = idx >> 3, c = (idx & 7) * 8;
            *(short8*)&ks[r * 64 + c] = *(const short8*)&kbuf[((size_t)bh * 8192 + nb + r) * 64 + c];
            *(short8*)&vs[r * 64 + c] = *(const short8*)&vbuf[((size_t)bh * 8192 + nb + r) * 64 + c];
        }
        __syncthreads();
        for (int n = 0; n < 64; ++n) {
            ushort4 kd = *(const ushort4*)&ks[n * 64 + d0];
            ushort4 ve = *(const ushort4*)&vs[n * 64 + e0];
            float kf[4] = {b2f(kd.x), b2f(kd.y), b2f(kd.z), b2f(kd.w)};
            float vf[4] = {b2f(ve.x), b2f(ve.y), b2f(ve.z), b2f(ve.w)};
#pragma unroll
            for (int i = 0; i < 4; ++i) {
#pragma unroll
                for (int j = 0; j < 4; ++j) acc[i][j] += kf[i] * vf[j];
            }
            if (do_ksum) {
#pragma unroll
                for (int i = 0; i < 4; ++i) kacc[i] += kf[i];
            }
        }
    }
#pragma unroll
    for (int i = 0; i < 4; ++i) {
        if (do_ksum) atomicAdd(&ksum[bh * 64 + d0 + i], kacc[i]);
#pragma unroll
        for (int j = 0; j < 4; ++j)
            atomicAdd(&kv[((size_t)bh * 64 + d0 + i) * 64 + e0 + j], acc[i][j]);
    }
}

// ---------------- out = (q @ kv) * z via MFMA, repack to [B][N][C] bf16 ----------------
__global__ __launch_bounds__(256) void out_kernel(
    const ushort_t* __restrict__ qbuf, const float* __restrict__ kv,
    const float* __restrict__ ksum, ushort_t* __restrict__ obuf)
{
    __shared__ float kvs[4096];
    __shared__ float ksums[64];

    const int bh = blockIdx.y, chunk = blockIdx.x, t = threadIdx.x;
    const int b = bh >> 4, h = bh & 15;
    const int wave = t >> 6, lane = t & 63;
    const int tok = lane & 15, fq = lane >> 4;

#pragma unroll
    for (int i = 0; i < 4; ++i) {
        int idx = (i * 256 + t) * 4;
        *(float4*)&kvs[idx] = *(const float4*)&kv[(size_t)bh * 4096 + idx];
    }
    if (t < 64) ksums[t] = ksum[bh * 64 + t];
    __syncthreads();

    short8 afr[4][2];
#pragma unroll
    for (int et = 0; et < 4; ++et)
#pragma unroll
        for (int kslice = 0; kslice < 2; ++kslice)
#pragma unroll
            for (int i = 0; i < 8; ++i) {
                const int d = kslice * 32 + fq * 8 + i;
                afr[et][kslice][i] = (short)f2b(kvs[d * 64 + et * 16 + tok]);
            }
    short8 zfr[2];
#pragma unroll
    for (int kslice = 0; kslice < 2; ++kslice)
#pragma unroll
        for (int i = 0; i < 8; ++i)
            zfr[kslice][i] = (short)f2b(ksums[kslice * 32 + fq * 8 + i]);

    const floatx4 z4 = {0.f, 0.f, 0.f, 0.f};
    const int nbase = chunk * 1024 + wave * 256;
    const ushort_t* qrow = qbuf + ((size_t)bh * 8192 + nbase + tok) * 64 + fq * 8;
    ushort_t* orow = obuf + ((size_t)b * 8192 + nbase + tok) * 1024 + h * 64 + fq * 4;

#pragma unroll 2
    for (int g = 0; g < 16; ++g) {
        short8 bf0 = *(const short8*)(qrow + (size_t)g * 16 * 64);
        short8 bf1 = *(const short8*)(qrow + (size_t)g * 16 * 64 + 32);

        floatx4 az = __builtin_amdgcn_mfma_f32_16x16x32_bf16(zfr[0], bf0, z4, 0, 0, 0);
        az = __builtin_amdgcn_mfma_f32_16x16x32_bf16(zfr[1], bf1, az, 0, 0, 0);

        floatx4 ad[4];
#pragma unroll
        for (int et = 0; et < 4; ++et) {
            ad[et] = __builtin_amdgcn_mfma_f32_16x16x32_bf16(afr[et][0], bf0, z4, 0, 0, 0);
            ad[et] = __builtin_amdgcn_mfma_f32_16x16x32_bf16(afr[et][1], bf1, ad[et], 0, 0, 0);
        }

        const float zi = 1.f / (az[0] + 1e-8f);
#pragma unroll
        for (int et = 0; et < 4; ++et) {
            ushort4 o;
            o.x = f2b(ad[et][0] * zi);
            o.y = f2b(ad[et][1] * zi);
            o.z = f2b(ad[et][2] * zi);
            o.w = f2b(ad[et][3] * zi);
            *(ushort4*)&orow[(size_t)g * 16 * 1024 + et * 16] = o;
        }
    }
}

// ---------------- launch ----------------

extern "C" void kernel_launch(void* const* d_in, const int* in_sizes, int n_in,
                              void* d_out, int out_size, void* d_ws, size_t ws_size,
                              hipStream_t stream) {
    const float* x      = (const float*)d_in[0];
    const float* w_qkv  = (const float*)d_in[1];
    const float* b_qkv  = (const float*)d_in[2];
    const float* w_proj = (const float*)d_in[3];
    const float* b_proj = (const float*)d_in[4];
    float* out = (float*)d_out;

    const size_t XE = (size_t)32768 * 1024;

    char* ws = (char*)d_ws;
    ushort_t* xb   = (ushort_t*)ws;  ws += XE * 2;
    ushort_t* wqT  = (ushort_t*)ws;  ws += (size_t)3072 * 1024 * 2;
    ushort_t* wpT  = (ushort_t*)ws;  ws += (size_t)1024 * 1024 * 2;
    ushort_t* qkvb = (ushort_t*)ws;  ws += 3 * XE * 2;   // [3][64][8192][64] scatter
    ushort_t* ob   = (ushort_t*)ws;  ws += XE * 2;       // [32768][1024]
    float*    kv   = (float*)ws;     ws += (size_t)64 * 64 * 64 * 4;
    float*    ksum = (float*)ws;     ws += (size_t)64 * 64 * 4;

    (void)hipFuncSetAttribute(reinterpret_cast<const void*>(gemm256<0>),
                              hipFuncAttributeMaxDynamicSharedMemorySize, 131072);
    (void)hipFuncSetAttribute(reinterpret_cast<const void*>(gemm256<1>),
                              hipFuncAttributeMaxDynamicSharedMemorySize, 131072);

    zero_f32<<<dim3((64 * 64 * 64 + 64 * 64 + 255) / 256), dim3(256), 0, stream>>>(kv, 64 * 64 * 64 + 64 * 64);
    conv_bf16<<<dim3(2048), dim3(256), 0, stream>>>(x, xb, (int)(XE / 8));
    transpose_conv<<<dim3(96, 32), dim3(32, 8), 0, stream>>>(w_qkv, wqT, 1024, 3072);
    transpose_conv<<<dim3(32, 32), dim3(32, 8), 0, stream>>>(w_proj, wpT, 1024, 1024);

    // qkv: M=32768, Nt=3072 -> 12*128 = 1536 blocks
    gemm256<0><<<dim3(1536), dim3(512), 131072, stream>>>(xb, wqT, b_qkv, qkvb, nullptr, 3072, 12);

    kv_kernel<<<dim3(16, 64), dim3(256), 0, stream>>>(qkvb + XE, qkvb + 2 * XE, kv, ksum);
    out_kernel<<<dim3(8, 64), dim3(256), 0, stream>>>(qkvb, kv, ksum, ob);

    // proj: M=32768, Nt=1024 -> 4*128 = 512 blocks
    gemm256<1><<<dim3(512), dim3(512), 131072, stream>>>(ob, wpT, b_proj, nullptr, out, 1024, 4);
}

// Round 7
// 507.532 us; speedup vs baseline: 1.0536x; 1.0536x over previous
//
#include <hip/hip_runtime.h>
#include <hip/hip_bf16.h>
#include <stdint.h>

typedef unsigned short ushort_t;
typedef __attribute__((ext_vector_type(8))) short short8;
typedef __attribute__((ext_vector_type(4))) float floatx4;

__device__ __forceinline__ ushort_t f2b(float f) {
    unsigned u = __float_as_uint(f);
    unsigned r = (u + 0x7FFFu + ((u >> 16) & 1u)) >> 16;
    return (ushort_t)r;
}
__device__ __forceinline__ float b2f(ushort_t h) {
    return __uint_as_float(((unsigned)h) << 16);
}
__device__ __forceinline__ float elu1(float f) {
    return (f > 0.f) ? (f + 1.f) : __expf(f);
}

#define GLDS16(srcp, dstp)                                                          \
    __builtin_amdgcn_global_load_lds(                                               \
        (const __attribute__((address_space(1))) unsigned int*)(srcp),              \
        (__attribute__((address_space(3))) unsigned int*)(dstp), 16, 0, 0)

// ---------------- conversion kernels ----------------

__global__ void conv_bf16(const float* __restrict__ in, ushort_t* __restrict__ out, int n8) {
    for (int i = blockIdx.x * blockDim.x + threadIdx.x; i < n8; i += gridDim.x * blockDim.x) {
        const float4 f0 = *(const float4*)&in[(size_t)i * 8];
        const float4 f1 = *(const float4*)&in[(size_t)i * 8 + 4];
        ushort4 o0, o1;
        o0.x = f2b(f0.x); o0.y = f2b(f0.y); o0.z = f2b(f0.z); o0.w = f2b(f0.w);
        o1.x = f2b(f1.x); o1.y = f2b(f1.y); o1.z = f2b(f1.z); o1.w = f2b(f1.w);
        *(ushort4*)&out[(size_t)i * 8]     = o0;
        *(ushort4*)&out[(size_t)i * 8 + 4] = o1;
    }
}

__global__ void transpose_conv(const float* __restrict__ in, ushort_t* __restrict__ out,
                               int R, int C) {
    __shared__ float tile[32][33];
    int c0 = blockIdx.x * 32, r0 = blockIdx.y * 32;
    int tx = threadIdx.x, ty = threadIdx.y;
#pragma unroll
    for (int k = 0; k < 4; ++k) {
        int a = ty * 4 + k;
        tile[a][tx] = in[(size_t)(r0 + a) * C + c0 + tx];
    }
    __syncthreads();
#pragma unroll
    for (int k = 0; k < 4; ++k) {
        int a = ty * 4 + k;
        out[(size_t)(c0 + a) * R + r0 + tx] = f2b(tile[tx][a]);
    }
}

__global__ void zero_f32(float* __restrict__ p, int n) {
    int i = blockIdx.x * blockDim.x + threadIdx.x;
    if (i < n) p[i] = 0.f;
}

// ---------------- 256x256 8-phase GEMM (16x16x32): C = A @ Bt^T, K = 1024 ----------------
// Swapped-operand MFMA: lane holds 4 consecutive n-columns -> packed/scalar stores.
// MODE 0: qkv epilogue: bias; q -> elu+1, packed [bh][n][64]; k -> elu+1, TRANSPOSED
//         [bh][d][n]; v -> TRANSPOSED [bh][d][n].  (base, base+XE, base+2XE)
// MODE 1: proj epilogue: bias; fp32 linear [M][Nt]
template<int MODE>
__global__ __launch_bounds__(512, 2) void gemm256(
    const ushort_t* __restrict__ A, const ushort_t* __restrict__ Bt,
    const float* __restrict__ bias,
    ushort_t* __restrict__ out_u16, float* __restrict__ out_f32,
    int Nt, int nbx)
{
    extern __shared__ ushort_t lds[];   // 65536 elements = 128 KiB
    constexpr int KK = 1024;
    constexpr size_t XEc = (size_t)32768 * 1024;

    const int tid  = threadIdx.x;
    const int wave = tid >> 6;
    const int lane = tid & 63;
    const int wm_i = wave >> 2;
    const int wn_i = wave & 3;
    const int fr   = lane & 15;
    const int fq   = lane >> 4;

    // XCD-bijective block swizzle (grid % 8 == 0)
    const int nwg = (int)gridDim.x;
    const int bid = (int)blockIdx.x;
    const int swz = (bid & 7) * (nwg >> 3) + (bid >> 3);
    const int bx = swz % nbx, by = swz / nbx;
    const int m0 = by * 256, n0 = bx * 256;

    // staging per-thread constants
    const int trow = tid >> 3;
    const int csw  = ((tid & 7) ^ (trow & 7)) << 3;
    const int tcolB = ((tid >> 8) << 6) + (trow & 31);

    const ushort_t* sa = A  + (size_t)(m0 + trow)  * KK + csw;
    const ushort_t* sb = Bt + (size_t)(n0 + tcolB) * KK + csw;

    const int dstA = wave * 512;
    const int dstB = 16384 + wave * 512;

    const int sw0 = (fq ^ (fr & 7)) << 3;
    const int sw1 = sw0 ^ 32;
    const int abase = (wm_i * 64 + fr) * 64;
    const int bbase = (wn_i * 32 + fr) * 64;
    int loA0[2][2], loA1[2][2], loB0[2][2], loB1[2][2];
#pragma unroll
    for (int bf = 0; bf < 2; ++bf)
#pragma unroll
        for (int q = 0; q < 2; ++q) {
            loA0[bf][q] = bf * 32768 + q * 8192 + abase + sw0;
            loA1[bf][q] = bf * 32768 + q * 8192 + abase + sw1;
            loB0[bf][q] = bf * 32768 + 16384 + q * 8192 + bbase + sw0;
            loB1[bf][q] = bf * 32768 + 16384 + q * 8192 + bbase + sw1;
        }

    floatx4 acc[8][4];
    const floatx4 z4 = {0.f, 0.f, 0.f, 0.f};
#pragma unroll
    for (int i = 0; i < 8; ++i)
#pragma unroll
        for (int j = 0; j < 4; ++j) acc[i][j] = z4;

    short8 a[4][2], b[2][2];

    auto stageA = [&](int buf, int h, int ko) {
        ushort_t* d = lds + buf * 32768 + h * 8192 + dstA;
        GLDS16(sa + h * (64 * KK) + ko, d);
        GLDS16(sa + h * (64 * KK) + 128 * KK + ko, d + 4096);
    };
    auto stageB = [&](int buf, int h, int ko) {
        ushort_t* d = lds + buf * 32768 + h * 8192 + dstB;
        GLDS16(sb + h * (32 * KK) + ko, d);
        GLDS16(sb + h * (32 * KK) + 128 * KK + ko, d + 4096);
    };
    auto loadA = [&](int buf, int qr) {
        const int o0 = loA0[buf][qr], o1 = loA1[buf][qr];
#pragma unroll
        for (int i = 0; i < 4; ++i) {
            a[i][0] = *(const short8*)(lds + o0 + i * 1024);
            a[i][1] = *(const short8*)(lds + o1 + i * 1024);
        }
    };
    auto loadB = [&](int buf, int qc) {
        const int o0 = loB0[buf][qc], o1 = loB1[buf][qc];
#pragma unroll
        for (int j = 0; j < 2; ++j) {
            b[j][0] = *(const short8*)(lds + o0 + j * 1024);
            b[j][1] = *(const short8*)(lds + o1 + j * 1024);
        }
    };
    // swapped operands: D^T -> lane fq*4+r indexes n (cols), fr indexes m (rows)
    auto mma = [&](int qr, int qc) {
#pragma unroll
        for (int i = 0; i < 4; ++i)
#pragma unroll
            for (int j = 0; j < 2; ++j) {
                acc[qr * 4 + i][qc * 2 + j] =
                    __builtin_amdgcn_mfma_f32_16x16x32_bf16(b[j][0], a[i][0], acc[qr * 4 + i][qc * 2 + j], 0, 0, 0);
                acc[qr * 4 + i][qc * 2 + j] =
                    __builtin_amdgcn_mfma_f32_16x16x32_bf16(b[j][1], a[i][1], acc[qr * 4 + i][qc * 2 + j], 0, 0, 0);
            }
    };

#define PRIO1() __builtin_amdgcn_s_setprio(1)
#define BOUT()  __builtin_amdgcn_s_setprio(0); __builtin_amdgcn_s_barrier()
#define VM6()   asm volatile("s_waitcnt vmcnt(6)" ::: "memory")
#define VM0()   asm volatile("s_waitcnt vmcnt(0)" ::: "memory")

    // prologue: stream order per tile = [A0, B1, A1, B0]
    stageA(0, 0, 0);
    stageB(0, 1, 0);
    stageA(0, 1, 0);
    stageB(0, 0, 0);
    stageA(1, 0, 64);
    stageB(1, 1, 64);
    stageA(1, 1, 64);
    VM6();
    __builtin_amdgcn_s_barrier();

    int ko = 0;
    for (int pr = 0; pr < 7; ++pr, ko += 128) {
        // ---- tile t0 (buf0) ----
        loadA(0, 0); loadB(0, 0);
        stageB(1, 0, ko + 64);
        PRIO1(); mma(0, 0); BOUT();

        loadB(0, 1);
        stageA(0, 0, ko + 128);
        PRIO1(); mma(0, 1); BOUT();

        loadA(0, 1);
        stageB(0, 1, ko + 128);
        PRIO1(); mma(1, 1); BOUT();

        loadB(0, 0);
        stageA(0, 1, ko + 128);
        PRIO1(); mma(1, 0); __builtin_amdgcn_s_setprio(0); VM6();
        __builtin_amdgcn_s_barrier();

        // ---- tile t0+1 (buf1) ----
        loadA(1, 0); loadB(1, 0);
        stageB(0, 0, ko + 128);
        PRIO1(); mma(0, 0); BOUT();

        loadB(1, 1);
        stageA(1, 0, ko + 192);
        PRIO1(); mma(0, 1); BOUT();

        loadA(1, 1);
        stageB(1, 1, ko + 192);
        PRIO1(); mma(1, 1); BOUT();

        loadB(1, 0);
        stageA(1, 1, ko + 192);
        PRIO1(); mma(1, 0); __builtin_amdgcn_s_setprio(0); VM6();
        __builtin_amdgcn_s_barrier();
    }

    // peeled last iteration: tiles 14 (buf0), 15 (buf1); ko == 896
    loadA(0, 0); loadB(0, 0);
    stageB(1, 0, 960);
    PRIO1(); mma(0, 0); BOUT();

    loadB(0, 1);
    PRIO1(); mma(0, 1); BOUT();

    loadA(0, 1);
    PRIO1(); mma(1, 1); BOUT();

    loadB(0, 0);
    PRIO1(); mma(1, 0); __builtin_amdgcn_s_setprio(0); VM0();
    __builtin_amdgcn_s_barrier();

    loadA(1, 0); loadB(1, 0);
    PRIO1(); mma(0, 0); BOUT();

    loadB(1, 1);
    PRIO1(); mma(0, 1); BOUT();

    loadA(1, 1);
    PRIO1(); mma(1, 1); BOUT();

    loadB(1, 0);
    PRIO1(); mma(1, 0);
    __builtin_amdgcn_s_setprio(0);

#undef PRIO1
#undef BOUT
#undef VM6
#undef VM0

    // epilogue (swapped layout):
    //   m = m0 + wm_i*128 + (ri>>2)*64 + (ri&3)*16 + fr   (token row)
    //   n = n0 + wn_i*64 + (cj>>1)*32 + (cj&1)*16 + fq*4 + r   (qkv col)
    float4 bv[4];
#pragma unroll
    for (int cj = 0; cj < 4; ++cj) {
        const int nb = n0 + wn_i * 64 + (cj >> 1) * 32 + (cj & 1) * 16 + fq * 4;
        bv[cj] = *(const float4*)&bias[nb];
    }
#pragma unroll
    for (int ri = 0; ri < 8; ++ri) {
        const int m = m0 + wm_i * 128 + (ri >> 2) * 64 + (ri & 3) * 16 + fr;
#pragma unroll
        for (int cj = 0; cj < 4; ++cj) {
            const int col = n0 + wn_i * 64 + (cj >> 1) * 32 + (cj & 1) * 16 + fq * 4;
            float v0 = acc[ri][cj][0] + bv[cj].x;
            float v1 = acc[ri][cj][1] + bv[cj].y;
            float v2 = acc[ri][cj][2] + bv[cj].z;
            float v3 = acc[ri][cj][3] + bv[cj].w;
            if (MODE == 0) {
                const int s  = col >> 10;           // 0=q 1=k 2=v (uniform per block)
                const int c  = col & 1023;
                const int h  = c >> 6;
                const int d  = c & 63;
                const int bb = m >> 13;
                const int n  = m & 8191;
                const int bh = bb * 16 + h;
                if (s == 0) {
                    v0 = elu1(v0); v1 = elu1(v1); v2 = elu1(v2); v3 = elu1(v3);
                    ushort4 o;
                    o.x = f2b(v0); o.y = f2b(v1); o.z = f2b(v2); o.w = f2b(v3);
                    *(ushort4*)&out_u16[((size_t)bh * 8192 + n) * 64 + d] = o;
                } else if (s == 1) {
                    v0 = elu1(v0); v1 = elu1(v1); v2 = elu1(v2); v3 = elu1(v3);
                    ushort_t* kT = out_u16 + XEc;
                    kT[((size_t)bh * 64 + d + 0) * 8192 + n] = f2b(v0);
                    kT[((size_t)bh * 64 + d + 1) * 8192 + n] = f2b(v1);
                    kT[((size_t)bh * 64 + d + 2) * 8192 + n] = f2b(v2);
                    kT[((size_t)bh * 64 + d + 3) * 8192 + n] = f2b(v3);
                } else {
                    ushort_t* vT = out_u16 + 2 * XEc;
                    vT[((size_t)bh * 64 + d + 0) * 8192 + n] = f2b(v0);
                    vT[((size_t)bh * 64 + d + 1) * 8192 + n] = f2b(v1);
                    vT[((size_t)bh * 64 + d + 2) * 8192 + n] = f2b(v2);
                    vT[((size_t)bh * 64 + d + 3) * 8192 + n] = f2b(v3);
                }
            } else {
                float4 o; o.x = v0; o.y = v1; o.z = v2; o.w = v3;
                *(float4*)&out_f32[(size_t)m * Nt + col] = o;
            }
        }
    }
}

// ---------------- kv = kT @ vT^T via MFMA (+ ksum via ones-B) ----------------
// kT/vT: [64 bh][64 d/e][8192 n] bf16.  kv: [bh][d][e] fp32.  ksum: [bh][d] fp32.
// grid (8, 64); 4 waves, wave-private n-subs (no barrier in loop); block LDS-reduce.
__global__ __launch_bounds__(256) void kvg_kernel(
    const ushort_t* __restrict__ kT, const ushort_t* __restrict__ vT,
    float* __restrict__ kv, float* __restrict__ ksum)
{
    __shared__ ushort_t stg[4][2][4096] __attribute__((aligned(16)));  // 64 KiB
    __shared__ float ksr[4][64];

    const int bh = blockIdx.y, chunk = blockIdx.x, t = threadIdx.x;
    const int wave = t >> 6, lane = t & 63;
    const int tok = lane & 15, fq = lane >> 4;

    // frag read offsets (chunk-XOR swizzle S(r) = (r&7) ^ (((r>>3)&3)<<1))
    int roff[4][2];
#pragma unroll
    for (int rt = 0; rt < 4; ++rt) {
        const int row = rt * 16 + tok;
        const int S = (row & 7) ^ (((row >> 3) & 3) << 1);
#pragma unroll
        for (int s = 0; s < 2; ++s)
            roff[rt][s] = row * 64 + (((4 * s + fq) ^ S) << 3);
    }
    const int Sw = (lane & 7) ^ (((lane >> 3) & 3) << 1);

    short8 ones;
#pragma unroll
    for (int i = 0; i < 8; ++i) ones[i] = (short)0x3F80;

    floatx4 av[4][4], ak[4];
    const floatx4 z4 = {0.f, 0.f, 0.f, 0.f};
#pragma unroll
    for (int i = 0; i < 4; ++i) {
        ak[i] = z4;
#pragma unroll
        for (int j = 0; j < 4; ++j) av[i][j] = z4;
    }

    const ushort_t* srcK = kT + ((size_t)bh * 64 + lane) * 8192 + chunk * 1024;
    const ushort_t* srcV = vT + ((size_t)bh * 64 + lane) * 8192 + chunk * 1024;
    ushort_t* dk = &stg[wave][0][lane * 64];
    ushort_t* dv = &stg[wave][1][lane * 64];

#pragma unroll 1
    for (int s2 = 0; s2 < 4; ++s2) {
        const int ns = (wave * 4 + s2) * 64;
        // stage one 64x64 sub-tile of kT and vT (wave-private, swizzled)
#pragma unroll
        for (int g = 0; g < 8; ++g) {
            const int ph = (g ^ Sw) << 3;
            *(short8*)&dk[ph] = *(const short8*)&srcK[ns + g * 8];
            *(short8*)&dv[ph] = *(const short8*)&srcV[ns + g * 8];
        }
#pragma unroll
        for (int s = 0; s < 2; ++s) {
            short8 afr[4], bfr[4];
#pragma unroll
            for (int rt = 0; rt < 4; ++rt)
                afr[rt] = *(const short8*)&stg[wave][0][roff[rt][s]];
#pragma unroll
            for (int rt = 0; rt < 4; ++rt)
                bfr[rt] = *(const short8*)&stg[wave][1][roff[rt][s]];
#pragma unroll
            for (int dt = 0; dt < 4; ++dt) {
                ak[dt] = __builtin_amdgcn_mfma_f32_16x16x32_bf16(afr[dt], ones, ak[dt], 0, 0, 0);
#pragma unroll
                for (int et = 0; et < 4; ++et)
                    av[dt][et] = __builtin_amdgcn_mfma_f32_16x16x32_bf16(afr[dt], bfr[et], av[dt][et], 0, 0, 0);
            }
        }
    }

    // wave-private partial dump into own stg region (16 KiB = 4096 f32)
    float* red = (float*)&stg[wave][0][0];
#pragma unroll
    for (int dt = 0; dt < 4; ++dt)
#pragma unroll
        for (int et = 0; et < 4; ++et)
#pragma unroll
            for (int r = 0; r < 4; ++r)
                red[(dt * 16 + fq * 4 + r) * 64 + et * 16 + tok] = av[dt][et][r];
    if (tok == 0) {
#pragma unroll
        for (int dt = 0; dt < 4; ++dt)
#pragma unroll
            for (int r = 0; r < 4; ++r)
                ksr[wave][dt * 16 + fq * 4 + r] = ak[dt][r];
    }
    __syncthreads();

    const float* base = (const float*)&stg[0][0][0];
#pragma unroll
    for (int j = 0; j < 4; ++j) {
        const int idx = t * 16 + j * 4;
        float4 s0 = *(const float4*)&base[0 * 4096 + idx];
        float4 s1 = *(const float4*)&base[1 * 4096 + idx];
        float4 s2 = *(const float4*)&base[2 * 4096 + idx];
        float4 s3 = *(const float4*)&base[3 * 4096 + idx];
        atomicAdd(&kv[(size_t)bh * 4096 + idx + 0], s0.x + s1.x + s2.x + s3.x);
        atomicAdd(&kv[(size_t)bh * 4096 + idx + 1], s0.y + s1.y + s2.y + s3.y);
        atomicAdd(&kv[(size_t)bh * 4096 + idx + 2], s0.z + s1.z + s2.z + s3.z);
        atomicAdd(&kv[(size_t)bh * 4096 + idx + 3], s0.w + s1.w + s2.w + s3.w);
    }
    if (t < 64) {
        float s = ksr[0][t] + ksr[1][t] + ksr[2][t] + ksr[3][t];
        atomicAdd(&ksum[bh * 64 + t], s);
    }
}

// ---------------- out = (q @ kv) * z via MFMA, repack to [B][N][C] bf16 ----------------
__global__ __launch_bounds__(256) void out_kernel(
    const ushort_t* __restrict__ qbuf, const float* __restrict__ kv,
    const float* __restrict__ ksum, ushort_t* __restrict__ obuf)
{
    __shared__ float kvs[4096];
    __shared__ float ksums[64];

    const int bh = blockIdx.y, chunk = blockIdx.x, t = threadIdx.x;
    const int b = bh >> 4, h = bh & 15;
    const int wave = t >> 6, lane = t & 63;
    const int tok = lane & 15, fq = lane >> 4;

#pragma unroll
    for (int i = 0; i < 4; ++i) {
        int idx = (i * 256 + t) * 4;
        *(float4*)&kvs[idx] = *(const float4*)&kv[(size_t)bh * 4096 + idx];
    }
    if (t < 64) ksums[t] = ksum[bh * 64 + t];
    __syncthreads();

    short8 afr[4][2];
#pragma unroll
    for (int et = 0; et < 4; ++et)
#pragma unroll
        for (int kslice = 0; kslice < 2; ++kslice)
#pragma unroll
            for (int i = 0; i < 8; ++i) {
                const int d = kslice * 32 + fq * 8 + i;
                afr[et][kslice][i] = (short)f2b(kvs[d * 64 + et * 16 + tok]);
            }
    short8 zfr[2];
#pragma unroll
    for (int kslice = 0; kslice < 2; ++kslice)
#pragma unroll
        for (int i = 0; i < 8; ++i)
            zfr[kslice][i] = (short)f2b(ksums[kslice * 32 + fq * 8 + i]);

    const floatx4 z4 = {0.f, 0.f, 0.f, 0.f};
    const int nbase = chunk * 1024 + wave * 256;
    const ushort_t* qrow = qbuf + ((size_t)bh * 8192 + nbase + tok) * 64 + fq * 8;
    ushort_t* orow = obuf + ((size_t)b * 8192 + nbase + tok) * 1024 + h * 64 + fq * 4;

#pragma unroll 2
    for (int g = 0; g < 16; ++g) {
        short8 bf0 = *(const short8*)(qrow + (size_t)g * 16 * 64);
        short8 bf1 = *(const short8*)(qrow + (size_t)g * 16 * 64 + 32);

        floatx4 az = __builtin_amdgcn_mfma_f32_16x16x32_bf16(zfr[0], bf0, z4, 0, 0, 0);
        az = __builtin_amdgcn_mfma_f32_16x16x32_bf16(zfr[1], bf1, az, 0, 0, 0);

        floatx4 ad[4];
#pragma unroll
        for (int et = 0; et < 4; ++et) {
            ad[et] = __builtin_amdgcn_mfma_f32_16x16x32_bf16(afr[et][0], bf0, z4, 0, 0, 0);
            ad[et] = __builtin_amdgcn_mfma_f32_16x16x32_bf16(afr[et][1], bf1, ad[et], 0, 0, 0);
        }

        const float zi = 1.f / (az[0] + 1e-8f);
#pragma unroll
        for (int et = 0; et < 4; ++et) {
            ushort4 o;
            o.x = f2b(ad[et][0] * zi);
            o.y = f2b(ad[et][1] * zi);
            o.z = f2b(ad[et][2] * zi);
            o.w = f2b(ad[et][3] * zi);
            *(ushort4*)&orow[(size_t)g * 16 * 1024 + et * 16] = o;
        }
    }
}

// ---------------- launch ----------------

extern "C" void kernel_launch(void* const* d_in, const int* in_sizes, int n_in,
                              void* d_out, int out_size, void* d_ws, size_t ws_size,
                              hipStream_t stream) {
    const float* x      = (const float*)d_in[0];
    const float* w_qkv  = (const float*)d_in[1];
    const float* b_qkv  = (const float*)d_in[2];
    const float* w_proj = (const float*)d_in[3];
    const float* b_proj = (const float*)d_in[4];
    float* out = (float*)d_out;

    const size_t XE = (size_t)32768 * 1024;

    char* ws = (char*)d_ws;
    ushort_t* xb   = (ushort_t*)ws;  ws += XE * 2;
    ushort_t* wqT  = (ushort_t*)ws;  ws += (size_t)3072 * 1024 * 2;
    ushort_t* wpT  = (ushort_t*)ws;  ws += (size_t)1024 * 1024 * 2;
    ushort_t* qkvb = (ushort_t*)ws;  ws += 3 * XE * 2;   // q [bh][n][d]; kT,vT [bh][d][n]
    ushort_t* ob   = (ushort_t*)ws;  ws += XE * 2;       // [32768][1024]
    float*    kv   = (float*)ws;     ws += (size_t)64 * 64 * 64 * 4;
    float*    ksum = (float*)ws;     ws += (size_t)64 * 64 * 4;

    (void)hipFuncSetAttribute(reinterpret_cast<const void*>(gemm256<0>),
                              hipFuncAttributeMaxDynamicSharedMemorySize, 131072);
    (void)hipFuncSetAttribute(reinterpret_cast<const void*>(gemm256<1>),
                              hipFuncAttributeMaxDynamicSharedMemorySize, 131072);

    zero_f32<<<dim3((64 * 64 * 64 + 64 * 64 + 255) / 256), dim3(256), 0, stream>>>(kv, 64 * 64 * 64 + 64 * 64);
    conv_bf16<<<dim3(2048), dim3(256), 0, stream>>>(x, xb, (int)(XE / 8));
    transpose_conv<<<dim3(96, 32), dim3(32, 8), 0, stream>>>(w_qkv, wqT, 1024, 3072);
    transpose_conv<<<dim3(32, 32), dim3(32, 8), 0, stream>>>(w_proj, wpT, 1024, 1024);

    // qkv: M=32768, Nt=3072 -> 12*128 = 1536 blocks
    gemm256<0><<<dim3(1536), dim3(512), 131072, stream>>>(xb, wqT, b_qkv, qkvb, nullptr, 3072, 12);

    kvg_kernel<<<dim3(8, 64), dim3(256), 0, stream>>>(qkvb + XE, qkvb + 2 * XE, kv, ksum);
    out_kernel<<<dim3(8, 64), dim3(256), 0, stream>>>(qkvb, kv, ksum, ob);

    // proj: M=32768, Nt=1024 -> 4*128 = 512 blocks
    gemm256<1><<<dim3(512), dim3(512), 131072, stream>>>(ob, wpT, b_proj, nullptr, out, 1024, 4);
}

// Round 8
// 475.217 us; speedup vs baseline: 1.1253x; 1.0680x over previous
//
#include <hip/hip_runtime.h>
#include <hip/hip_bf16.h>
#include <stdint.h>

typedef unsigned short ushort_t;
typedef __attribute__((ext_vector_type(8))) short short8;
typedef __attribute__((ext_vector_type(4))) float floatx4;

__device__ __forceinline__ ushort_t f2b(float f) {
    unsigned u = __float_as_uint(f);
    unsigned r = (u + 0x7FFFu + ((u >> 16) & 1u)) >> 16;
    return (ushort_t)r;
}
__device__ __forceinline__ float b2f(ushort_t h) {
    return __uint_as_float(((unsigned)h) << 16);
}
__device__ __forceinline__ float elu1(float f) {
    return (f > 0.f) ? (f + 1.f) : __expf(f);
}

#define GLDS16(srcp, dstp)                                                          \
    __builtin_amdgcn_global_load_lds(                                               \
        (const __attribute__((address_space(1))) unsigned int*)(srcp),              \
        (__attribute__((address_space(3))) unsigned int*)(dstp), 16, 0, 0)

// ---------------- conversion kernels ----------------

__global__ void conv_bf16(const float* __restrict__ in, ushort_t* __restrict__ out, int n8) {
    for (int i = blockIdx.x * blockDim.x + threadIdx.x; i < n8; i += gridDim.x * blockDim.x) {
        const float4 f0 = *(const float4*)&in[(size_t)i * 8];
        const float4 f1 = *(const float4*)&in[(size_t)i * 8 + 4];
        ushort4 o0, o1;
        o0.x = f2b(f0.x); o0.y = f2b(f0.y); o0.z = f2b(f0.z); o0.w = f2b(f0.w);
        o1.x = f2b(f1.x); o1.y = f2b(f1.y); o1.z = f2b(f1.z); o1.w = f2b(f1.w);
        *(ushort4*)&out[(size_t)i * 8]     = o0;
        *(ushort4*)&out[(size_t)i * 8 + 4] = o1;
    }
}

__global__ void transpose_conv(const float* __restrict__ in, ushort_t* __restrict__ out,
                               int R, int C) {
    __shared__ float tile[32][33];
    int c0 = blockIdx.x * 32, r0 = blockIdx.y * 32;
    int tx = threadIdx.x, ty = threadIdx.y;
#pragma unroll
    for (int k = 0; k < 4; ++k) {
        int a = ty * 4 + k;
        tile[a][tx] = in[(size_t)(r0 + a) * C + c0 + tx];
    }
    __syncthreads();
#pragma unroll
    for (int k = 0; k < 4; ++k) {
        int a = ty * 4 + k;
        out[(size_t)(c0 + a) * R + r0 + tx] = f2b(tile[tx][a]);
    }
}

__global__ void zero_f32(float* __restrict__ p, int n) {
    int i = blockIdx.x * blockDim.x + threadIdx.x;
    if (i < n) p[i] = 0.f;
}

// ---------------- persistent 256x256 8-phase GEMM (16x16x32): C = A @ Bt^T, K=1024 ----------------
// 256 persistent blocks; each streams nt output tiles. The stage stream is continuous
// across tile boundaries (last iteration stages next tile's kt0/kt1).
// MODE 0: qkv epilogue: bias + elu+1 on q,k; packed 8B scatter to [3][bh][8192][64]
// MODE 1: proj epilogue: bias; fp32 linear [M][Nt]
template<int MODE>
__global__ __launch_bounds__(512, 2) void gemm256(
    const ushort_t* __restrict__ A, const ushort_t* __restrict__ Bt,
    const float* __restrict__ bias,
    ushort_t* __restrict__ out_u16, float* __restrict__ out_f32,
    int Nt, int nbx, int nt)
{
    extern __shared__ ushort_t lds[];   // 65536 elements = 128 KiB
    constexpr int KK = 1024;

    const int tid  = threadIdx.x;
    const int wave = tid >> 6;
    const int lane = tid & 63;
    const int wm_i = wave >> 2;
    const int wn_i = wave & 3;
    const int fr   = lane & 15;
    const int fq   = lane >> 4;

    const int bid  = (int)blockIdx.x;
    const int bswz = ((bid & 7) << 5) + (bid >> 3);   // XCD-contiguous tile chunks
    const int ntiles = nt << 8;                        // nt * 256

    // staging per-thread constants
    const int trow = tid >> 3;
    const int csw  = ((tid & 7) ^ (trow & 7)) << 3;
    const int tcolB = ((tid >> 8) << 6) + (trow & 31);

    const int dstA = wave * 512;
    const int dstB = 16384 + wave * 512;

    const int sw0 = (fq ^ (fr & 7)) << 3;
    const int sw1 = sw0 ^ 32;
    const int abase = (wm_i * 64 + fr) * 64;
    const int bbase = (wn_i * 32 + fr) * 64;
    int loA0[2][2], loA1[2][2], loB0[2][2], loB1[2][2];
#pragma unroll
    for (int bf = 0; bf < 2; ++bf)
#pragma unroll
        for (int q = 0; q < 2; ++q) {
            loA0[bf][q] = bf * 32768 + q * 8192 + abase + sw0;
            loA1[bf][q] = bf * 32768 + q * 8192 + abase + sw1;
            loB0[bf][q] = bf * 32768 + 16384 + q * 8192 + bbase + sw0;
            loB1[bf][q] = bf * 32768 + 16384 + q * 8192 + bbase + sw1;
        }

    floatx4 acc[8][4];
    const floatx4 z4 = {0.f, 0.f, 0.f, 0.f};
#pragma unroll
    for (int i = 0; i < 8; ++i)
#pragma unroll
        for (int j = 0; j < 4; ++j) acc[i][j] = z4;

    short8 a[4][2], b[2][2];

    auto tilebase = [&](int t, const ushort_t*& sA, const ushort_t*& sB, int& mm, int& nn) {
        const int byy = t / nbx;
        const int bxx = t - byy * nbx;
        mm = byy << 8; nn = bxx << 8;
        sA = A  + (size_t)(mm + trow)  * KK + csw;
        sB = Bt + (size_t)(nn + tcolB) * KK + csw;
    };

    auto stageA = [&](const ushort_t* sp, int buf, int h, int ko) {
        ushort_t* d = lds + buf * 32768 + h * 8192 + dstA;
        GLDS16(sp + h * (64 * KK) + ko, d);
        GLDS16(sp + h * (64 * KK) + 128 * KK + ko, d + 4096);
    };
    auto stageB = [&](const ushort_t* sp, int buf, int h, int ko) {
        ushort_t* d = lds + buf * 32768 + h * 8192 + dstB;
        GLDS16(sp + h * (32 * KK) + ko, d);
        GLDS16(sp + h * (32 * KK) + 128 * KK + ko, d + 4096);
    };
    auto loadA = [&](int buf, int qr) {
        const int o0 = loA0[buf][qr], o1 = loA1[buf][qr];
#pragma unroll
        for (int i = 0; i < 4; ++i) {
            a[i][0] = *(const short8*)(lds + o0 + i * 1024);
            a[i][1] = *(const short8*)(lds + o1 + i * 1024);
        }
    };
    auto loadB = [&](int buf, int qc) {
        const int o0 = loB0[buf][qc], o1 = loB1[buf][qc];
#pragma unroll
        for (int j = 0; j < 2; ++j) {
            b[j][0] = *(const short8*)(lds + o0 + j * 1024);
            b[j][1] = *(const short8*)(lds + o1 + j * 1024);
        }
    };
    // swapped operands: D^T -> lane fq*4+r indexes n (cols), fr indexes m (rows)
    auto mma = [&](int qr, int qc) {
#pragma unroll
        for (int i = 0; i < 4; ++i)
#pragma unroll
            for (int j = 0; j < 2; ++j) {
                acc[qr * 4 + i][qc * 2 + j] =
                    __builtin_amdgcn_mfma_f32_16x16x32_bf16(b[j][0], a[i][0], acc[qr * 4 + i][qc * 2 + j], 0, 0, 0);
                acc[qr * 4 + i][qc * 2 + j] =
                    __builtin_amdgcn_mfma_f32_16x16x32_bf16(b[j][1], a[i][1], acc[qr * 4 + i][qc * 2 + j], 0, 0, 0);
            }
    };

    auto epilogue = [&](int m0, int n0) {
        float4 bv[4];
#pragma unroll
        for (int cj = 0; cj < 4; ++cj) {
            const int nb = n0 + wn_i * 64 + (cj >> 1) * 32 + (cj & 1) * 16 + fq * 4;
            bv[cj] = *(const float4*)&bias[nb];
        }
#pragma unroll
        for (int ri = 0; ri < 8; ++ri) {
            const int m = m0 + wm_i * 128 + (ri >> 2) * 64 + (ri & 3) * 16 + fr;
#pragma unroll
            for (int cj = 0; cj < 4; ++cj) {
                const int col = n0 + wn_i * 64 + (cj >> 1) * 32 + (cj & 1) * 16 + fq * 4;
                float v0 = acc[ri][cj][0] + bv[cj].x;
                float v1 = acc[ri][cj][1] + bv[cj].y;
                float v2 = acc[ri][cj][2] + bv[cj].z;
                float v3 = acc[ri][cj][3] + bv[cj].w;
                if (MODE == 0) {
                    const int s  = col >> 10;
                    const int c  = col & 1023;
                    const int h  = c >> 6;
                    const int d  = c & 63;
                    const int bb = m >> 13;
                    const int n  = m & 8191;
                    if (s < 2) { v0 = elu1(v0); v1 = elu1(v1); v2 = elu1(v2); v3 = elu1(v3); }
                    ushort4 o;
                    o.x = f2b(v0); o.y = f2b(v1); o.z = f2b(v2); o.w = f2b(v3);
                    *(ushort4*)&out_u16[(((size_t)s * 64 + bb * 16 + h) * 8192 + n) * 64 + d] = o;
                } else {
                    float4 o; o.x = v0; o.y = v1; o.z = v2; o.w = v3;
                    *(float4*)&out_f32[(size_t)m * Nt + col] = o;
                }
            }
        }
    };

#define PRIO1() __builtin_amdgcn_s_setprio(1)
#define BOUT()  __builtin_amdgcn_s_setprio(0); __builtin_amdgcn_s_barrier()
#define VM6()   asm volatile("s_waitcnt vmcnt(6)" ::: "memory")

    // tile pointer state
    const ushort_t *saC, *sbC, *saN, *sbN;
    int m0, n0, m0N, n0N;
    int tC = bswz;
    tilebase(tC, saC, sbC, m0, n0);
    int tN = (tC + 256 < ntiles) ? tC + 256 : tC;
    tilebase(tN, saN, sbN, m0N, n0N);

    // one-time prologue: tile tC, kt0 [A0,B1,A1,B0] -> buf0; kt1 [A0,B1,A1] -> buf1
    stageA(saC, 0, 0, 0);
    stageB(sbC, 0, 1, 0);
    stageA(saC, 0, 1, 0);
    stageB(sbC, 0, 0, 0);
    stageA(saC, 1, 0, 64);
    stageB(sbC, 1, 1, 64);
    stageA(saC, 1, 1, 64);
    VM6();
    __builtin_amdgcn_s_barrier();

    for (int ot = 0; ot < nt; ++ot) {
        int ko = 0;
        for (int pr = 0; pr < 7; ++pr, ko += 128) {
            // ---- tile t0 (buf0) ----
            loadA(0, 0); loadB(0, 0);
            stageB(sbC, 1, 0, ko + 64);
            PRIO1(); mma(0, 0); BOUT();

            loadB(0, 1);
            stageA(saC, 0, 0, ko + 128);
            PRIO1(); mma(0, 1); BOUT();

            loadA(0, 1);
            stageB(sbC, 0, 1, ko + 128);
            PRIO1(); mma(1, 1); BOUT();

            loadB(0, 0);
            stageA(saC, 0, 1, ko + 128);
            PRIO1(); mma(1, 0); __builtin_amdgcn_s_setprio(0); VM6();
            __builtin_amdgcn_s_barrier();

            // ---- tile t0+1 (buf1) ----
            loadA(1, 0); loadB(1, 0);
            stageB(sbC, 0, 0, ko + 128);
            PRIO1(); mma(0, 0); BOUT();

            loadB(1, 1);
            stageA(saC, 1, 0, ko + 192);
            PRIO1(); mma(0, 1); BOUT();

            loadA(1, 1);
            stageB(sbC, 1, 1, ko + 192);
            PRIO1(); mma(1, 1); BOUT();

            loadB(1, 0);
            stageA(saC, 1, 1, ko + 192);
            PRIO1(); mma(1, 0); __builtin_amdgcn_s_setprio(0); VM6();
            __builtin_amdgcn_s_barrier();
        }

        // ---- last iteration: kt14 (buf0), kt15 (buf1); stages kt16/17 = next tile kt0/1 ----
        loadA(0, 0); loadB(0, 0);
        stageB(sbC, 1, 0, 960);          // B0(kt15) -> buf1
        PRIO1(); mma(0, 0); BOUT();

        loadB(0, 1);
        stageA(saN, 0, 0, 0);            // A0(next kt0) -> buf0
        PRIO1(); mma(0, 1); BOUT();

        loadA(0, 1);
        stageB(sbN, 0, 1, 0);            // B1(next kt0) -> buf0
        PRIO1(); mma(1, 1); BOUT();

        loadB(0, 0);
        stageA(saN, 0, 1, 0);            // A1(next kt0) -> buf0
        PRIO1(); mma(1, 0); __builtin_amdgcn_s_setprio(0); VM6();
        __builtin_amdgcn_s_barrier();

        loadA(1, 0); loadB(1, 0);
        stageB(sbN, 0, 0, 0);            // B0(next kt0) -> buf0
        PRIO1(); mma(0, 0); BOUT();

        loadB(1, 1);
        stageA(saN, 1, 0, 64);           // A0(next kt1) -> buf1
        PRIO1(); mma(0, 1); BOUT();

        loadA(1, 1);
        stageB(sbN, 1, 1, 64);           // B1(next kt1) -> buf1
        PRIO1(); mma(1, 1); BOUT();

        loadB(1, 0);
        stageA(saN, 1, 1, 64);           // A1(next kt1) -> buf1
        PRIO1(); mma(1, 0); __builtin_amdgcn_s_setprio(0); VM6();
        __builtin_amdgcn_s_barrier();

        // ---- epilogue (no LDS traffic; safe before other waves' next P1 stage) ----
        epilogue(m0, n0);
#pragma unroll
        for (int i = 0; i < 8; ++i)
#pragma unroll
            for (int j = 0; j < 4; ++j) acc[i][j] = z4;

        // advance tile state
        saC = saN; sbC = sbN; m0 = m0N; n0 = n0N; tC = tN;
        tN = (tC + 256 < ntiles) ? tC + 256 : tC;
        tilebase(tN, saN, sbN, m0N, n0N);
    }

#undef PRIO1
#undef BOUT
#undef VM6
}

// ---------------- kv = k^T v  (+ ksum) per (b,h) ----------------
__global__ __launch_bounds__(256) void kv_kernel(
    const ushort_t* __restrict__ kbuf, const ushort_t* __restrict__ vbuf,
    float* __restrict__ kv, float* __restrict__ ksum)
{
    __shared__ ushort_t ks[64 * 64] __attribute__((aligned(16)));
    __shared__ ushort_t vs[64 * 64] __attribute__((aligned(16)));

    const int bh = blockIdx.y, chunk = blockIdx.x, t = threadIdx.x;
    const int d0 = (t >> 4) * 4, e0 = (t & 15) * 4;
    const bool do_ksum = (t & 15) == 0;

    float acc[4][4];
#pragma unroll
    for (int i = 0; i < 4; ++i)
#pragma unroll
        for (int j = 0; j < 4; ++j) acc[i][j] = 0.f;
    float kacc[4] = {0.f, 0.f, 0.f, 0.f};

    for (int sub = 0; sub < 8; ++sub) {
        const int nb = chunk * 512 + sub * 64;
        __syncthreads();
#pragma unroll
        for (int p = 0; p < 2; ++p) {
            int idx = p * 256 + t;
            int r = idx >> 3, c = (idx & 7) * 8;
            *(short8*)&ks[r * 64 + c] = *(const short8*)&kbuf[((size_t)bh * 8192 + nb + r) * 64 + c];
            *(short8*)&vs[r * 64 + c] = *(const short8*)&vbuf[((size_t)bh * 8192 + nb + r) * 64 + c];
        }
        __syncthreads();
        for (int n = 0; n < 64; ++n) {
            ushort4 kd = *(const ushort4*)&ks[n * 64 + d0];
            ushort4 ve = *(const ushort4*)&vs[n * 64 + e0];
            float kf[4] = {b2f(kd.x), b2f(kd.y), b2f(kd.z), b2f(kd.w)};
            float vf[4] = {b2f(ve.x), b2f(ve.y), b2f(ve.z), b2f(ve.w)};
#pragma unroll
            for (int i = 0; i < 4; ++i) {
#pragma unroll
                for (int j = 0; j < 4; ++j) acc[i][j] += kf[i] * vf[j];
            }
            if (do_ksum) {
#pragma unroll
                for (int i = 0; i < 4; ++i) kacc[i] += kf[i];
            }
        }
    }
#pragma unroll
    for (int i = 0; i < 4; ++i) {
        if (do_ksum) atomicAdd(&ksum[bh * 64 + d0 + i], kacc[i]);
#pragma unroll
        for (int j = 0; j < 4; ++j)
            atomicAdd(&kv[((size_t)bh * 64 + d0 + i) * 64 + e0 + j], acc[i][j]);
    }
}

// ---------------- out = (q @ kv) * z via MFMA, repack to [B][N][C] bf16 ----------------
__global__ __launch_bounds__(256) void out_kernel(
    const ushort_t* __restrict__ qbuf, const float* __restrict__ kv,
    const float* __restrict__ ksum, ushort_t* __restrict__ obuf)
{
    __shared__ float kvs[4096];
    __shared__ float ksums[64];

    const int bh = blockIdx.y, chunk = blockIdx.x, t = threadIdx.x;
    const int b = bh >> 4, h = bh & 15;
    const int wave = t >> 6, lane = t & 63;
    const int tok = lane & 15, fq = lane >> 4;

#pragma unroll
    for (int i = 0; i < 4; ++i) {
        int idx = (i * 256 + t) * 4;
        *(float4*)&kvs[idx] = *(const float4*)&kv[(size_t)bh * 4096 + idx];
    }
    if (t < 64) ksums[t] = ksum[bh * 64 + t];
    __syncthreads();

    short8 afr[4][2];
#pragma unroll
    for (int et = 0; et < 4; ++et)
#pragma unroll
        for (int kslice = 0; kslice < 2; ++kslice)
#pragma unroll
            for (int i = 0; i < 8; ++i) {
                const int d = kslice * 32 + fq * 8 + i;
                afr[et][kslice][i] = (short)f2b(kvs[d * 64 + et * 16 + tok]);
            }
    short8 zfr[2];
#pragma unroll
    for (int kslice = 0; kslice < 2; ++kslice)
#pragma unroll
        for (int i = 0; i < 8; ++i)
            zfr[kslice][i] = (short)f2b(ksums[kslice * 32 + fq * 8 + i]);

    const floatx4 z4 = {0.f, 0.f, 0.f, 0.f};
    const int nbase = chunk * 1024 + wave * 256;
    const ushort_t* qrow = qbuf + ((size_t)bh * 8192 + nbase + tok) * 64 + fq * 8;
    ushort_t* orow = obuf + ((size_t)b * 8192 + nbase + tok) * 1024 + h * 64 + fq * 4;

#pragma unroll 2
    for (int g = 0; g < 16; ++g) {
        short8 bf0 = *(const short8*)(qrow + (size_t)g * 16 * 64);
        short8 bf1 = *(const short8*)(qrow + (size_t)g * 16 * 64 + 32);

        floatx4 az = __builtin_amdgcn_mfma_f32_16x16x32_bf16(zfr[0], bf0, z4, 0, 0, 0);
        az = __builtin_amdgcn_mfma_f32_16x16x32_bf16(zfr[1], bf1, az, 0, 0, 0);

        floatx4 ad[4];
#pragma unroll
        for (int et = 0; et < 4; ++et) {
            ad[et] = __builtin_amdgcn_mfma_f32_16x16x32_bf16(afr[et][0], bf0, z4, 0, 0, 0);
            ad[et] = __builtin_amdgcn_mfma_f32_16x16x32_bf16(afr[et][1], bf1, ad[et], 0, 0, 0);
        }

        const float zi = 1.f / (az[0] + 1e-8f);
#pragma unroll
        for (int et = 0; et < 4; ++et) {
            ushort4 o;
            o.x = f2b(ad[et][0] * zi);
            o.y = f2b(ad[et][1] * zi);
            o.z = f2b(ad[et][2] * zi);
            o.w = f2b(ad[et][3] * zi);
            *(ushort4*)&orow[(size_t)g * 16 * 1024 + et * 16] = o;
        }
    }
}

// ---------------- launch ----------------

extern "C" void kernel_launch(void* const* d_in, const int* in_sizes, int n_in,
                              void* d_out, int out_size, void* d_ws, size_t ws_size,
                              hipStream_t stream) {
    const float* x      = (const float*)d_in[0];
    const float* w_qkv  = (const float*)d_in[1];
    const float* b_qkv  = (const float*)d_in[2];
    const float* w_proj = (const float*)d_in[3];
    const float* b_proj = (const float*)d_in[4];
    float* out = (float*)d_out;

    const size_t XE = (size_t)32768 * 1024;

    char* ws = (char*)d_ws;
    ushort_t* xb   = (ushort_t*)ws;  ws += XE * 2;
    ushort_t* wqT  = (ushort_t*)ws;  ws += (size_t)3072 * 1024 * 2;
    ushort_t* wpT  = (ushort_t*)ws;  ws += (size_t)1024 * 1024 * 2;
    ushort_t* qkvb = (ushort_t*)ws;  ws += 3 * XE * 2;   // [3][64][8192][64] scatter
    ushort_t* ob   = (ushort_t*)ws;  ws += XE * 2;       // [32768][1024]
    float*    kv   = (float*)ws;     ws += (size_t)64 * 64 * 64 * 4;
    float*    ksum = (float*)ws;     ws += (size_t)64 * 64 * 4;

    (void)hipFuncSetAttribute(reinterpret_cast<const void*>(gemm256<0>),
                              hipFuncAttributeMaxDynamicSharedMemorySize, 131072);
    (void)hipFuncSetAttribute(reinterpret_cast<const void*>(gemm256<1>),
                              hipFuncAttributeMaxDynamicSharedMemorySize, 131072);

    zero_f32<<<dim3((64 * 64 * 64 + 64 * 64 + 255) / 256), dim3(256), 0, stream>>>(kv, 64 * 64 * 64 + 64 * 64);
    conv_bf16<<<dim3(2048), dim3(256), 0, stream>>>(x, xb, (int)(XE / 8));
    transpose_conv<<<dim3(96, 32), dim3(32, 8), 0, stream>>>(w_qkv, wqT, 1024, 3072);
    transpose_conv<<<dim3(32, 32), dim3(32, 8), 0, stream>>>(w_proj, wpT, 1024, 1024);

    // qkv: 1536 tiles, 256 persistent blocks, nt=6
    gemm256<0><<<dim3(256), dim3(512), 131072, stream>>>(xb, wqT, b_qkv, qkvb, nullptr, 3072, 12, 6);

    kv_kernel<<<dim3(16, 64), dim3(256), 0, stream>>>(qkvb + XE, qkvb + 2 * XE, kv, ksum);
    out_kernel<<<dim3(8, 64), dim3(256), 0, stream>>>(qkvb, kv, ksum, ob);

    // proj: 512 tiles, 256 persistent blocks, nt=2
    gemm256<1><<<dim3(256), dim3(512), 131072, stream>>>(ob, wpT, b_proj, nullptr, out, 1024, 4, 2);
}